// Round 9
// baseline (86788.696 us; speedup 1.0000x reference)
//
#include <hip/hip_runtime.h>
#include <hip/hip_bf16.h>

#define N_NODES 16384
#define E_EDGESN (16384*32)
#define FEAT 512
#define EMB 256
#define HID 512
#define G4 2048      // 4*HID
#define XDIM 512     // 2*EMB
#define NWG 32       // worker workgroups
#define UPW 16       // hidden units per wg (16 x 32 = 512)

typedef __attribute__((ext_vector_type(8))) short bf16x8;
typedef __attribute__((ext_vector_type(4))) float f32x4;

__device__ __forceinline__ float b2f(unsigned short u) {
  union { unsigned int i; float f; } v; v.i = ((unsigned int)u) << 16; return v.f;
}
__device__ __forceinline__ unsigned short f2b(float f) {
  union { float f; unsigned int i; } v; v.f = f;
  unsigned int x = v.i;
  unsigned int r = (x + 0x7FFFu + ((x >> 16) & 1u)) >> 16;
  return (unsigned short)r;
}
__device__ __forceinline__ float fast_sigmoid(float x) {
  return __builtin_amdgcn_rcpf(1.0f + __expf(-x));
}
__device__ __forceinline__ float fast_tanh(float x) {
  return fmaf(-2.0f, __builtin_amdgcn_rcpf(1.0f + __expf(2.0f * x)), 1.0f);
}

// ---------------- K0: dtype detection (bf16 vs fp32 inputs) ----------------
__global__ __launch_bounds__(256) void k_detect(const unsigned* __restrict__ w,
                                                unsigned* __restrict__ flag) {
  __shared__ int cnt;
  if (threadIdx.x == 0) cnt = 0;
  __syncthreads();
  int hits = 0;
#pragma unroll
  for (int j = 0; j < 4; ++j) {
    unsigned wv = w[threadIdx.x * 4 + j];
    unsigned e = (wv >> 7) & 0xFFu;
    if ((e >= 90u && e <= 126u) || ((wv & 0xFFFFu) == 0u)) hits++;
  }
  atomicAdd(&cnt, hits);
  __syncthreads();
  if (threadIdx.x == 0) *flag = (cnt < 512) ? 1u : 0u;   // 1 = fp32 inputs
}

// ---------------- K1: canonicalize float tensor to bf16 ----------------
__global__ void k_convert(const void* __restrict__ src, unsigned short* __restrict__ dst,
                          int n, const unsigned* __restrict__ flag) {
  int i = blockIdx.x * blockDim.x + threadIdx.x;
  if (i >= n) return;
  if (*flag) dst[i] = f2b(((const float*)src)[i]);
  else       dst[i] = ((const unsigned short*)src)[i];
}

// ---------------- K2: tag histogram scatter ----------------
__global__ void k_hist(const int* __restrict__ nid, const int* __restrict__ ntag,
                       unsigned* __restrict__ hist) {
  int e = blockIdx.x * blockDim.x + threadIdx.x;
  if (e < E_EDGESN)
    atomicAdd(&hist[(size_t)nid[e] * FEAT + ntag[e]], 1u);
}

// ---------------- K3: build x = [node_emb | nb_emb] as bf16 ----------------
__global__ __launch_bounds__(256) void k_build_x(
    const int* __restrict__ tags, const unsigned* __restrict__ hist,
    const unsigned short* __restrict__ Wemb, const unsigned short* __restrict__ bemb,
    unsigned short* __restrict__ x) {
  __shared__ int f_lds[160];
  __shared__ float c_lds[160];
  __shared__ int nlist;
  int n = blockIdx.x, c = threadIdx.x;
  if (c == 0) nlist = 0;
  __syncthreads();
  for (int f = c; f < FEAT; f += 256) {
    unsigned cnt = hist[(size_t)n * FEAT + f];
    if (cnt) {
      int idx = atomicAdd(&nlist, 1);
      if (idx < 160) { f_lds[idx] = f; c_lds[idx] = (float)cnt; }
    }
  }
  __syncthreads();
  int m = nlist; if (m > 160) m = 160;
  float be = b2f(bemb[c]);
  int tg = tags[n];
  x[(size_t)n * XDIM + c] = f2b(b2f(Wemb[(size_t)tg * EMB + c]) + be);
  float acc = be;
  for (int j = 0; j < m; ++j)
    acc += c_lds[j] * b2f(Wemb[(size_t)f_lds[j] * EMB + c]);
  x[(size_t)n * XDIM + EMB + c] = f2b(acc);
}

// ---------------- K4: pre = x @ W_ih^T + b_lstm (MFMA bf16) ----------------
// Output PERMUTED: prep[t][unit*4 + gate]; gate = nn>>9, unit = nn&511.
__global__ __launch_bounds__(256) void k_gemm_pre(
    const unsigned short* __restrict__ x, const unsigned short* __restrict__ Wih,
    const unsigned short* __restrict__ blstm, unsigned short* __restrict__ pre) {
  int wave = threadIdx.x >> 6, lane = threadIdx.x & 63;
  int row = lane & 15, quad = lane >> 4;
  int mband = blockIdx.y * 64 + wave * 16;
  int nbase = blockIdx.x * 128;
  f32x4 acc[8] = {};
  const unsigned short* ap = x + (size_t)(mband + row) * XDIM + quad * 8;
  const unsigned short* bp0 = Wih + (size_t)(nbase + row) * XDIM + quad * 8;
  for (int kc = 0; kc < 16; ++kc) {
    bf16x8 af = *(const bf16x8*)(ap + kc * 32);
#pragma unroll
    for (int nt = 0; nt < 8; ++nt) {
      bf16x8 bf = *(const bf16x8*)(bp0 + (size_t)nt * 16 * XDIM + kc * 32);
      acc[nt] = __builtin_amdgcn_mfma_f32_16x16x32_bf16(af, bf, acc[nt], 0, 0, 0);
    }
  }
#pragma unroll
  for (int nt = 0; nt < 8; ++nt) {
    int nn = nbase + nt * 16 + row;
    float bv = b2f(blstm[nn]);
    int pn = ((nn & 511) << 2) | (nn >> 9);   // unit*4 + gate
#pragma unroll
    for (int i = 0; i < 4; ++i) {
      int mm = mband + quad * 4 + i;
      pre[(size_t)mm * G4 + pn] = f2b(acc[nt][i] + bv);
    }
  }
}

// ---------------- K5: minimal-protocol LLC-mailbox LSTM scan (v9) ----------
// 32 wgs x 256 thr, 1 wave/SIMD. 16-lane group owns one unit (4 gate rows,
// 128 fp32 W_hh in VGPRs, k contiguous [s*32,s*32+32)).
// h publication: ONE word per unit = (fp32 h & 0xFFFFFF00) | (t & 0xFF).
//   8-bit tag is sufficient: 2-slot ring bounds inter-wave skew to 2 steps,
//   so a slot only ever holds tags t or t-2 (differ mod 256). Poison 0xAA
//   can only false-match at t=170+k*256, by which time every cell has been
//   rewritten hundreds of times.
// NO LDS, NO barriers in the loop: each lane polls the 32 h-words of its own
// k-slice directly from the mailbox (16 dwordx2 sc0 sc1 loads, one vmcnt),
// consuming them straight into the matvec. Waves run decoupled; progress
// induction holds at wave granularity (every wave produces units).
// Fallback: after 64 fast tries, per-word agent-atomic spin (r3-proven
// encoding, same buffer) -> cannot hang.
__global__ __launch_bounds__(256, 1) void k_scan(
    const unsigned short* __restrict__ Whh, const unsigned short* __restrict__ prep,
    unsigned* __restrict__ hw, float* __restrict__ embed) {
  int tid = threadIdx.x, wg = blockIdx.x;
  int ug = tid >> 4;           // unit within wg [0,16)
  int s  = tid & 15;           // k-slice: k in [s*32, s*32+32)
  int lane = tid & 63;
  int unit = wg * UPW + ug;    // global unit [0,512)

  // W_hh rows for this unit's 4 gates, k contiguous
  float wreg[4][32];
#pragma unroll
  for (int g = 0; g < 4; ++g) {
    const unsigned* wp = (const unsigned*)(Whh + (size_t)(g * HID + unit) * HID) + s * 16;
#pragma unroll
    for (int j = 0; j < 16; ++j) {
      unsigned wv = wp[j];
      wreg[g][2 * j]     = b2f((unsigned short)(wv & 0xFFFFu));
      wreg[g][2 * j + 1] = b2f((unsigned short)(wv >> 16));
    }
  }

  // pre prefetch on s==1 lanes, 8-step blocks, shfl-broadcast each step
  unsigned pc0[8], pc1[8];
  if (s == 1) {
#pragma unroll
    for (int i = 0; i < 8; ++i) {
      const unsigned* pp = (const unsigned*)(prep + (size_t)i * G4 + (unsigned)unit * 4u);
      pc0[i] = pp[0]; pc1[i] = pp[1];
    }
  }
  int bsrc = (lane & 48) | 1;

  float cstate = 0.0f, eacc = 0.0f;
  unsigned long long hwB = (unsigned long long)hw;
  unsigned w32[32];
#pragma unroll
  for (int i = 0; i < 32; ++i) w32[i] = 0;   // h(-1) = 0 (denormal-zero words)

  for (int t = 0; t < N_NODES; ++t) {
    if (t > 0) {
      unsigned tagp = (unsigned)(t - 1) & 0xFFu;
      unsigned long long pa = hwB + (unsigned)(((t - 1) & 1) << 11) + (unsigned)s * 128u;
      unsigned long long r0,r1,r2,r3,r4,r5,r6,r7,r8,r9,r10,r11,r12,r13,r14,r15;
      int ok = 0;
      for (int tries = 0; tries < 64 && !ok; ++tries) {
        asm volatile(
          "global_load_dwordx2 %0, %16, off sc0 sc1\n\t"
          "global_load_dwordx2 %1, %16, off offset:8 sc0 sc1\n\t"
          "global_load_dwordx2 %2, %16, off offset:16 sc0 sc1\n\t"
          "global_load_dwordx2 %3, %16, off offset:24 sc0 sc1\n\t"
          "global_load_dwordx2 %4, %16, off offset:32 sc0 sc1\n\t"
          "global_load_dwordx2 %5, %16, off offset:40 sc0 sc1\n\t"
          "global_load_dwordx2 %6, %16, off offset:48 sc0 sc1\n\t"
          "global_load_dwordx2 %7, %16, off offset:56 sc0 sc1\n\t"
          "global_load_dwordx2 %8, %16, off offset:64 sc0 sc1\n\t"
          "global_load_dwordx2 %9, %16, off offset:72 sc0 sc1\n\t"
          "global_load_dwordx2 %10, %16, off offset:80 sc0 sc1\n\t"
          "global_load_dwordx2 %11, %16, off offset:88 sc0 sc1\n\t"
          "global_load_dwordx2 %12, %16, off offset:96 sc0 sc1\n\t"
          "global_load_dwordx2 %13, %16, off offset:104 sc0 sc1\n\t"
          "global_load_dwordx2 %14, %16, off offset:112 sc0 sc1\n\t"
          "global_load_dwordx2 %15, %16, off offset:120 sc0 sc1\n\t"
          "s_waitcnt vmcnt(0)"
          : "=&v"(r0), "=&v"(r1), "=&v"(r2), "=&v"(r3),
            "=&v"(r4), "=&v"(r5), "=&v"(r6), "=&v"(r7),
            "=&v"(r8), "=&v"(r9), "=&v"(r10), "=&v"(r11),
            "=&v"(r12), "=&v"(r13), "=&v"(r14), "=&v"(r15)
          : "v"(pa) : "memory");
        w32[0]=(unsigned)r0;  w32[1]=(unsigned)(r0>>32);
        w32[2]=(unsigned)r1;  w32[3]=(unsigned)(r1>>32);
        w32[4]=(unsigned)r2;  w32[5]=(unsigned)(r2>>32);
        w32[6]=(unsigned)r3;  w32[7]=(unsigned)(r3>>32);
        w32[8]=(unsigned)r4;  w32[9]=(unsigned)(r4>>32);
        w32[10]=(unsigned)r5; w32[11]=(unsigned)(r5>>32);
        w32[12]=(unsigned)r6; w32[13]=(unsigned)(r6>>32);
        w32[14]=(unsigned)r7; w32[15]=(unsigned)(r7>>32);
        w32[16]=(unsigned)r8; w32[17]=(unsigned)(r8>>32);
        w32[18]=(unsigned)r9; w32[19]=(unsigned)(r9>>32);
        w32[20]=(unsigned)r10; w32[21]=(unsigned)(r10>>32);
        w32[22]=(unsigned)r11; w32[23]=(unsigned)(r11>>32);
        w32[24]=(unsigned)r12; w32[25]=(unsigned)(r12>>32);
        w32[26]=(unsigned)r13; w32[27]=(unsigned)(r13>>32);
        w32[28]=(unsigned)r14; w32[29]=(unsigned)(r14>>32);
        w32[30]=(unsigned)r15; w32[31]=(unsigned)(r15>>32);
        unsigned m = 0;
#pragma unroll
        for (int i = 0; i < 32; ++i) m |= (w32[i] ^ tagp);
        ok = ((m & 0xFFu) == 0u);
      }
      if (!ok) {   // agent-atomic per-word spin: proven encoding, cannot hang
        unsigned* qp = (unsigned*)(uintptr_t)pa;
#pragma unroll
        for (int i = 0; i < 32; ++i) {
          unsigned v;
          do {
            v = __hip_atomic_load(qp + i, __ATOMIC_RELAXED, __HIP_MEMORY_SCOPE_AGENT);
          } while (((v ^ tagp) & 0xFFu) != 0u);
          w32[i] = v;
        }
      }
    }

    // ---- matvec: consume tagged words directly (low byte = tag ~ 2^-16 noise removed) ----
    float a0 = 0.f, a1 = 0.f, a2 = 0.f, a3 = 0.f;
#pragma unroll
    for (int j = 0; j < 32; ++j) {
      union { unsigned u; float f; } hv; hv.u = w32[j] & 0xFFFFFF00u;
      a0 = fmaf(wreg[0][j], hv.f, a0);
      a1 = fmaf(wreg[1][j], hv.f, a1);
      a2 = fmaf(wreg[2][j], hv.f, a2);
      a3 = fmaf(wreg[3][j], hv.f, a3);
    }
#pragma unroll
    for (int off = 1; off < 16; off <<= 1) {
      a0 += __shfl_xor(a0, off);
      a1 += __shfl_xor(a1, off);
      a2 += __shfl_xor(a2, off);
      a3 += __shfl_xor(a3, off);
    }

    // broadcast this step's pre words from the s==1 prefetch lane
    unsigned w0 = __shfl(pc0[t & 7], bsrc, 64);
    unsigned w1 = __shfl(pc1[t & 7], bsrc, 64);

    if (s == 0) {
      float gi = fast_sigmoid(a0 + b2f((unsigned short)(w0 & 0xFFFFu)));
      float gf = fast_sigmoid(a1 + b2f((unsigned short)(w0 >> 16)));
      float gg = fast_tanh   (a2 + b2f((unsigned short)(w1 & 0xFFFFu)));
      float go = fast_sigmoid(a3 + b2f((unsigned short)(w1 >> 16)));
      cstate = gf * cstate + gi * gg;
      float hn = go * fast_tanh(cstate);
      eacc += hn;
      if (t < N_NODES - 1) {
        union { float f; unsigned u; } cu; cu.f = hn;
        unsigned word = (cu.u & 0xFFFFFF00u) | ((unsigned)t & 0xFFu);
        unsigned long long sa = hwB + (unsigned)((t & 1) << 11) + (unsigned)unit * 4u;
        asm volatile("global_store_dword %0, %1, off sc0 sc1"
                     :: "v"(sa), "v"(word) : "memory");
      }
    }
    if (s == 1 && (t & 7) == 7) {   // prefetch next 8-step pre block
#pragma unroll
      for (int i = 0; i < 8; ++i) {
        int row = t + 1 + i;
        if (row >= N_NODES) row = 0;
        const unsigned* pp = (const unsigned*)(prep + (size_t)row * G4 + (unsigned)unit * 4u);
        pc0[i] = pp[0]; pc1[i] = pp[1];
      }
    }
  }
  if (s == 0) embed[unit] = eacc;
}

// ---------------- K6: MLP head + log_softmax ----------------
__global__ __launch_bounds__(512) void k_head(
    const float* __restrict__ embed, const unsigned short* __restrict__ W1,
    const unsigned short* __restrict__ b1, const unsigned short* __restrict__ W2,
    const unsigned short* __restrict__ b2, void* __restrict__ out,
    const unsigned* __restrict__ flag) {
  __shared__ float e_s[HID], h1_s[HID];
  __shared__ float lg[16];
  int tid = threadIdx.x;
  e_s[tid] = embed[tid];
  __syncthreads();
  float sum = b2f(b1[tid]);
  for (int i = 0; i < HID; ++i)
    sum += e_s[i] * b2f(W1[(size_t)i * HID + tid]);
  h1_s[tid] = fmaxf(sum, 0.0f);
  __syncthreads();
  if (tid < 10) {
    float l = b2f(b2[tid]);
    for (int j = 0; j < HID; ++j)
      l += h1_s[j] * b2f(W2[(size_t)j * 10 + tid]);
    lg[tid] = l;
  }
  __syncthreads();
  if (tid == 0) {
    float m = -1e30f;
    for (int c = 0; c < 10; ++c) m = fmaxf(m, lg[c]);
    float se = 0.f;
    for (int c = 0; c < 10; ++c) se += expf(lg[c] - m);
    float lse = m + logf(se);
    if (*flag) {
      for (int c = 0; c < 10; ++c) ((float*)out)[c] = lg[c] - lse;
    } else {
      for (int c = 0; c < 10; ++c) ((unsigned short*)out)[c] = f2b(lg[c] - lse);
    }
  }
}

extern "C" void kernel_launch(void* const* d_in, const int* in_sizes, int n_in,
                              void* d_out, int out_size, void* d_ws, size_t ws_size,
                              hipStream_t stream) {
  const int* node_tags = (const int*)d_in[0];
  const int* nid = (const int*)d_in[1];
  const int* ntag = (const int*)d_in[2];
  // d_in[3] = label, unused

  char* ws = (char*)d_ws;
  unsigned short* pre  = (unsigned short*)ws;                     // 67,108,864
  unsigned short* x    = (unsigned short*)(ws + 67108864);        // 16,777,216
  unsigned*       hist = (unsigned*)(ws + 83886080);              // 33,554,432
  char* tail = ws + 117440512;
  unsigned* hw    = (unsigned*)tail;                              // 4096 B mailbox: 2 slots x 512 words (NOT zeroed; poison-safe, see k_scan)
  unsigned* flag  = (unsigned*)(tail + 4096);
  float*    embed = (float*)(tail + 4352);                        // 2048 B
  char* wc = tail + 8192;                                         // bf16 weight copies
  unsigned short* Wemb_c  = (unsigned short*)(wc);
  unsigned short* bemb_c  = (unsigned short*)(wc + 262144);
  unsigned short* Wih_c   = (unsigned short*)(wc + 262656);
  unsigned short* Whh_c   = (unsigned short*)(wc + 2359808);
  unsigned short* blstm_c = (unsigned short*)(wc + 4456960);
  unsigned short* W1_c    = (unsigned short*)(wc + 4461056);
  unsigned short* b1_c    = (unsigned short*)(wc + 4985344);
  unsigned short* W2_c    = (unsigned short*)(wc + 4986368);
  unsigned short* b2_c    = (unsigned short*)(wc + 4996608);

  hipMemsetAsync(hist, 0, 33554432, stream);   // hist must start at zero

  k_detect<<<1, 256, 0, stream>>>((const unsigned*)d_in[6], flag);

  struct { const void* s; unsigned short* d; int n; } cv[9] = {
    { d_in[4],  Wemb_c,  FEAT * EMB },
    { d_in[5],  bemb_c,  EMB },
    { d_in[6],  Wih_c,   G4 * XDIM },
    { d_in[7],  Whh_c,   G4 * HID },
    { d_in[8],  blstm_c, G4 },
    { d_in[9],  W1_c,    HID * HID },
    { d_in[10], b1_c,    HID },
    { d_in[11], W2_c,    HID * 10 },
    { d_in[12], b2_c,    10 },
  };
  for (int i = 0; i < 9; ++i)
    k_convert<<<(cv[i].n + 255) / 256, 256, 0, stream>>>(cv[i].s, cv[i].d, cv[i].n, flag);

  k_hist<<<E_EDGESN / 256, 256, 0, stream>>>(nid, ntag, hist);
  k_build_x<<<N_NODES, 256, 0, stream>>>(node_tags, hist, Wemb_c, bemb_c, x);
  k_gemm_pre<<<dim3(G4 / 128, N_NODES / 64), 256, 0, stream>>>(x, Wih_c, blstm_c, pre);
  k_scan<<<NWG, 256, 0, stream>>>(Whh_c, pre, hw, embed);
  k_head<<<1, 512, 0, stream>>>(embed, W1_c, b1_c, W2_c, b2_c, d_out, flag);
}

// Round 10
// 29881.699 us; speedup vs baseline: 2.9044x; 2.9044x over previous
//
#include <hip/hip_runtime.h>
#include <hip/hip_bf16.h>

#define N_NODES 16384
#define E_EDGESN (16384*32)
#define FEAT 512
#define EMB 256
#define HID 512
#define G4 2048      // 4*HID
#define XDIM 512     // 2*EMB
#define NWG 32       // worker workgroups
#define UPW 16       // hidden units per wg (16 x 32 = 512)
#define NREP 4       // mailbox replicas (LLC slice spreading)
#define REPW 4096    // replica stride in words (16 KB)

typedef __attribute__((ext_vector_type(8))) short bf16x8;
typedef __attribute__((ext_vector_type(4))) float f32x4;

__device__ __forceinline__ float b2f(unsigned short u) {
  union { unsigned int i; float f; } v; v.i = ((unsigned int)u) << 16; return v.f;
}
__device__ __forceinline__ unsigned short f2b(float f) {
  union { float f; unsigned int i; } v; v.f = f;
  unsigned int x = v.i;
  unsigned int r = (x + 0x7FFFu + ((x >> 16) & 1u)) >> 16;
  return (unsigned short)r;
}
__device__ __forceinline__ float fast_sigmoid(float x) {
  return __builtin_amdgcn_rcpf(1.0f + __expf(-x));
}
__device__ __forceinline__ float fast_tanh(float x) {
  return fmaf(-2.0f, __builtin_amdgcn_rcpf(1.0f + __expf(2.0f * x)), 1.0f);
}

// ---------------- K0: dtype detection (bf16 vs fp32 inputs) ----------------
__global__ __launch_bounds__(256) void k_detect(const unsigned* __restrict__ w,
                                                unsigned* __restrict__ flag) {
  __shared__ int cnt;
  if (threadIdx.x == 0) cnt = 0;
  __syncthreads();
  int hits = 0;
#pragma unroll
  for (int j = 0; j < 4; ++j) {
    unsigned wv = w[threadIdx.x * 4 + j];
    unsigned e = (wv >> 7) & 0xFFu;
    if ((e >= 90u && e <= 126u) || ((wv & 0xFFFFu) == 0u)) hits++;
  }
  atomicAdd(&cnt, hits);
  __syncthreads();
  if (threadIdx.x == 0) *flag = (cnt < 512) ? 1u : 0u;   // 1 = fp32 inputs
}

// ---------------- K1: canonicalize float tensor to bf16 ----------------
__global__ void k_convert(const void* __restrict__ src, unsigned short* __restrict__ dst,
                          int n, const unsigned* __restrict__ flag) {
  int i = blockIdx.x * blockDim.x + threadIdx.x;
  if (i >= n) return;
  if (*flag) dst[i] = f2b(((const float*)src)[i]);
  else       dst[i] = ((const unsigned short*)src)[i];
}

// ---------------- K2: tag histogram scatter ----------------
__global__ void k_hist(const int* __restrict__ nid, const int* __restrict__ ntag,
                       unsigned* __restrict__ hist) {
  int e = blockIdx.x * blockDim.x + threadIdx.x;
  if (e < E_EDGESN)
    atomicAdd(&hist[(size_t)nid[e] * FEAT + ntag[e]], 1u);
}

// ---------------- K3: build x = [node_emb | nb_emb] as bf16 ----------------
__global__ __launch_bounds__(256) void k_build_x(
    const int* __restrict__ tags, const unsigned* __restrict__ hist,
    const unsigned short* __restrict__ Wemb, const unsigned short* __restrict__ bemb,
    unsigned short* __restrict__ x) {
  __shared__ int f_lds[160];
  __shared__ float c_lds[160];
  __shared__ int nlist;
  int n = blockIdx.x, c = threadIdx.x;
  if (c == 0) nlist = 0;
  __syncthreads();
  for (int f = c; f < FEAT; f += 256) {
    unsigned cnt = hist[(size_t)n * FEAT + f];
    if (cnt) {
      int idx = atomicAdd(&nlist, 1);
      if (idx < 160) { f_lds[idx] = f; c_lds[idx] = (float)cnt; }
    }
  }
  __syncthreads();
  int m = nlist; if (m > 160) m = 160;
  float be = b2f(bemb[c]);
  int tg = tags[n];
  x[(size_t)n * XDIM + c] = f2b(b2f(Wemb[(size_t)tg * EMB + c]) + be);
  float acc = be;
  for (int j = 0; j < m; ++j)
    acc += c_lds[j] * b2f(Wemb[(size_t)f_lds[j] * EMB + c]);
  x[(size_t)n * XDIM + EMB + c] = f2b(acc);
}

// ---------------- K4: pre = x @ W_ih^T + b_lstm (MFMA bf16) ----------------
// Output PERMUTED: prep[t][unit*4 + gate]; gate = nn>>9, unit = nn&511.
__global__ __launch_bounds__(256) void k_gemm_pre(
    const unsigned short* __restrict__ x, const unsigned short* __restrict__ Wih,
    const unsigned short* __restrict__ blstm, unsigned short* __restrict__ pre) {
  int wave = threadIdx.x >> 6, lane = threadIdx.x & 63;
  int row = lane & 15, quad = lane >> 4;
  int mband = blockIdx.y * 64 + wave * 16;
  int nbase = blockIdx.x * 128;
  f32x4 acc[8] = {};
  const unsigned short* ap = x + (size_t)(mband + row) * XDIM + quad * 8;
  const unsigned short* bp0 = Wih + (size_t)(nbase + row) * XDIM + quad * 8;
  for (int kc = 0; kc < 16; ++kc) {
    bf16x8 af = *(const bf16x8*)(ap + kc * 32);
#pragma unroll
    for (int nt = 0; nt < 8; ++nt) {
      bf16x8 bf = *(const bf16x8*)(bp0 + (size_t)nt * 16 * XDIM + kc * 32);
      acc[nt] = __builtin_amdgcn_mfma_f32_16x16x32_bf16(af, bf, acc[nt], 0, 0, 0);
    }
  }
#pragma unroll
  for (int nt = 0; nt < 8; ++nt) {
    int nn = nbase + nt * 16 + row;
    float bv = b2f(blstm[nn]);
    int pn = ((nn & 511) << 2) | (nn >> 9);   // unit*4 + gate
#pragma unroll
    for (int i = 0; i < 4; ++i) {
      int mm = mband + quad * 4 + i;
      pre[(size_t)mm * G4 + pn] = f2b(acc[nt][i] + bv);
    }
  }
}

// ---------------- K5: replicated-mailbox LLC LSTM scan (v10) ----------------
// 32 wgs x 256 thr (1 wave/SIMD). 16-lane group owns one unit; 128 fp32
// weights in VGPRs, k interleaved k = 32j + 2s + {0,1} (r7-proven layout).
// h publication: ONE word/unit = (fp32 h & 0xFFFFFF00) | (t & 0xFF)
//   (24-bit h + 8-bit tag packing numerically validated in r9).
//   NREP=4 replica mailboxes spaced 16 KB apart spread the LLC slices;
//   producers (gates computed redundantly on all 16 lanes -> identical
//   cstate) store 2 replicas each from lanes s==0 and s==8.
// consumers: wg g polls ONLY replica g&3 -> one 8-B agent-scope relaxed
//   atomic load per thread per try (the r3/r4-proven encoding, the ONLY
//   fabric that ever worked). LDS-share + syncthreads, conflict-free
//   interleaved float2 matvec. No fallback tiers needed: the hot path IS
//   the safe path; cannot hang.
// Ring safety (2 slots, 8-bit tag): per-wg skew <= 2 steps by induction
//   (store of t follows poll of t-1); slot holds tag t or t-2 only.
//   Poison 0xAA is overwritten in both slots by t=1, before tag 170 recurs.
__global__ __launch_bounds__(256, 1) void k_scan(
    const unsigned short* __restrict__ Whh, const unsigned short* __restrict__ prep,
    unsigned* __restrict__ hw, float* __restrict__ embed) {
  __shared__ float h_lds[HID];
  int tid = threadIdx.x, wg = blockIdx.x;
  int ug = tid >> 4;           // unit within wg [0,16)
  int s  = tid & 15;           // k-slice
  int lane = tid & 63;
  int unit = wg * UPW + ug;    // global unit [0,512)

  // W_hh rows for this unit's 4 gates, k interleaved: k = 32j + 2s + {0,1}
  float wreg[4][32];
#pragma unroll
  for (int g = 0; g < 4; ++g) {
    const unsigned* wp = (const unsigned*)(Whh + (size_t)(g * HID + unit) * HID);
#pragma unroll
    for (int j = 0; j < 16; ++j) {
      unsigned wv = wp[16 * j + s];        // elements 32j+2s, 32j+2s+1
      wreg[g][2 * j]     = b2f((unsigned short)(wv & 0xFFFFu));
      wreg[g][2 * j + 1] = b2f((unsigned short)(wv >> 16));
    }
  }

  // pre prefetch on s==4 lanes, 8-step blocks, shfl-broadcast each step
  unsigned pc0[8], pc1[8];
  if (s == 4) {
#pragma unroll
    for (int i = 0; i < 8; ++i) {
      const unsigned* pp = (const unsigned*)(prep + (size_t)i * G4 + (unsigned)unit * 4u);
      pc0[i] = pp[0]; pc1[i] = pp[1];
    }
  }
  int bsrc = (lane & 48) | 4;

  float cstate = 0.0f, eacc = 0.0f;
  h_lds[tid] = 0.0f;
  h_lds[256 + tid] = 0.0f;
  __syncthreads();

  unsigned myrep = (unsigned)(wg & (NREP - 1));

  for (int t = 0; t < N_NODES; ++t) {
    // ---- matvec over h(t-1): conflict-free float2, 4-way broadcast ----
    float a0 = 0.f, a1 = 0.f, a2 = 0.f, a3 = 0.f;
    const float2* hb = (const float2*)h_lds;
#pragma unroll
    for (int j = 0; j < 16; ++j) {
      float2 hv = hb[j * 16 + s];
      a0 += wreg[0][2*j] * hv.x + wreg[0][2*j+1] * hv.y;
      a1 += wreg[1][2*j] * hv.x + wreg[1][2*j+1] * hv.y;
      a2 += wreg[2][2*j] * hv.x + wreg[2][2*j+1] * hv.y;
      a3 += wreg[3][2*j] * hv.x + wreg[3][2*j+1] * hv.y;
    }
#pragma unroll
    for (int off = 1; off < 16; off <<= 1) {
      a0 += __shfl_xor(a0, off);   // all 16 lanes end with identical sums
      a1 += __shfl_xor(a1, off);
      a2 += __shfl_xor(a2, off);
      a3 += __shfl_xor(a3, off);
    }

    // broadcast this step's pre words from the s==4 prefetch lane
    unsigned w0 = __shfl(pc0[t & 7], bsrc, 64);
    unsigned w1 = __shfl(pc1[t & 7], bsrc, 64);

    // ---- gates: computed redundantly on ALL 16 lanes (identical inputs
    // -> bit-identical cstate on every lane; enables parallel replica stores)
    float gi = fast_sigmoid(a0 + b2f((unsigned short)(w0 & 0xFFFFu)));
    float gf = fast_sigmoid(a1 + b2f((unsigned short)(w0 >> 16)));
    float gg = fast_tanh   (a2 + b2f((unsigned short)(w1 & 0xFFFFu)));
    float go = fast_sigmoid(a3 + b2f((unsigned short)(w1 >> 16)));
    cstate = gf * cstate + gi * gg;
    float hn = go * fast_tanh(cstate);
    if (s == 0) eacc += hn;

    unsigned tagw = (unsigned)t & 0xFFu;
    if (t < N_NODES - 1) {
      union { float f; unsigned u; } cu; cu.f = hn;
      unsigned word = (cu.u & 0xFFFFFF00u) | tagw;
      unsigned slotw = ((unsigned)t & 1u) << 9;          // slot offset in words
      if (s == 0) {        // replicas 0,1
        __hip_atomic_store(&hw[0 * REPW + slotw + unit], word,
                           __ATOMIC_RELAXED, __HIP_MEMORY_SCOPE_AGENT);
        __hip_atomic_store(&hw[1 * REPW + slotw + unit], word,
                           __ATOMIC_RELAXED, __HIP_MEMORY_SCOPE_AGENT);
      } else if (s == 8) { // replicas 2,3
        __hip_atomic_store(&hw[2 * REPW + slotw + unit], word,
                           __ATOMIC_RELAXED, __HIP_MEMORY_SCOPE_AGENT);
        __hip_atomic_store(&hw[3 * REPW + slotw + unit], word,
                           __ATOMIC_RELAXED, __HIP_MEMORY_SCOPE_AGENT);
      }
    }
    if (s == 4 && (t & 7) == 7) {   // prefetch next 8-step pre block
#pragma unroll
      for (int i = 0; i < 8; ++i) {
        int row = t + 1 + i;
        if (row >= N_NODES) row = 0;
        const unsigned* pp = (const unsigned*)(prep + (size_t)row * G4 + (unsigned)unit * 4u);
        pc0[i] = pp[0]; pc1[i] = pp[1];
      }
    }

    if (t < N_NODES - 1) {
      // poll own replica: thread covers units 2*tid, 2*tid+1 (one 8-B load)
      unsigned long long* qp = (unsigned long long*)
          (hw + myrep * REPW + (((unsigned)t & 1u) << 9)) + tid;
      unsigned v0, v1;
      int tries = 0;
      for (;;) {
        unsigned long long v = __hip_atomic_load(qp, __ATOMIC_RELAXED,
                                                 __HIP_MEMORY_SCOPE_AGENT);
        v0 = (unsigned)v; v1 = (unsigned)(v >> 32);
        if ((((v0 ^ tagw) | (v1 ^ tagw)) & 0xFFu) == 0u) break;
        if (++tries > 128) __builtin_amdgcn_s_sleep(1);
      }
      h_lds[2 * tid]     = __uint_as_float(v0 & 0xFFFFFF00u);
      h_lds[2 * tid + 1] = __uint_as_float(v1 & 0xFFFFFF00u);
      __syncthreads();
    }
  }
  if (s == 0) embed[unit] = eacc;
}

// ---------------- K6: MLP head + log_softmax ----------------
__global__ __launch_bounds__(512) void k_head(
    const float* __restrict__ embed, const unsigned short* __restrict__ W1,
    const unsigned short* __restrict__ b1, const unsigned short* __restrict__ W2,
    const unsigned short* __restrict__ b2, void* __restrict__ out,
    const unsigned* __restrict__ flag) {
  __shared__ float e_s[HID], h1_s[HID];
  __shared__ float lg[16];
  int tid = threadIdx.x;
  e_s[tid] = embed[tid];
  __syncthreads();
  float sum = b2f(b1[tid]);
  for (int i = 0; i < HID; ++i)
    sum += e_s[i] * b2f(W1[(size_t)i * HID + tid]);
  h1_s[tid] = fmaxf(sum, 0.0f);
  __syncthreads();
  if (tid < 10) {
    float l = b2f(b2[tid]);
    for (int j = 0; j < HID; ++j)
      l += h1_s[j] * b2f(W2[(size_t)j * 10 + tid]);
    lg[tid] = l;
  }
  __syncthreads();
  if (tid == 0) {
    float m = -1e30f;
    for (int c = 0; c < 10; ++c) m = fmaxf(m, lg[c]);
    float se = 0.f;
    for (int c = 0; c < 10; ++c) se += expf(lg[c] - m);
    float lse = m + logf(se);
    if (*flag) {
      for (int c = 0; c < 10; ++c) ((float*)out)[c] = lg[c] - lse;
    } else {
      for (int c = 0; c < 10; ++c) ((unsigned short*)out)[c] = f2b(lg[c] - lse);
    }
  }
}

extern "C" void kernel_launch(void* const* d_in, const int* in_sizes, int n_in,
                              void* d_out, int out_size, void* d_ws, size_t ws_size,
                              hipStream_t stream) {
  const int* node_tags = (const int*)d_in[0];
  const int* nid = (const int*)d_in[1];
  const int* ntag = (const int*)d_in[2];
  // d_in[3] = label, unused

  char* ws = (char*)d_ws;
  unsigned short* pre  = (unsigned short*)ws;                     // 67,108,864
  unsigned short* x    = (unsigned short*)(ws + 67108864);        // 16,777,216
  unsigned*       hist = (unsigned*)(ws + 83886080);              // 33,554,432
  char* tail = ws + 117440512;
  unsigned* hw    = (unsigned*)tail;                              // 64 KB: 4 replicas x 16 KB stride (2 slots x 512 words each; NOT zeroed - poison-safe)
  unsigned* flag  = (unsigned*)(tail + 65536);
  float*    embed = (float*)(tail + 65792);                       // 2048 B
  char* wc = tail + 69632;                                        // bf16 weight copies
  unsigned short* Wemb_c  = (unsigned short*)(wc);
  unsigned short* bemb_c  = (unsigned short*)(wc + 262144);
  unsigned short* Wih_c   = (unsigned short*)(wc + 262656);
  unsigned short* Whh_c   = (unsigned short*)(wc + 2359808);
  unsigned short* blstm_c = (unsigned short*)(wc + 4456960);
  unsigned short* W1_c    = (unsigned short*)(wc + 4461056);
  unsigned short* b1_c    = (unsigned short*)(wc + 4985344);
  unsigned short* W2_c    = (unsigned short*)(wc + 4986368);
  unsigned short* b2_c    = (unsigned short*)(wc + 4996608);

  hipMemsetAsync(hist, 0, 33554432, stream);   // hist must start at zero

  k_detect<<<1, 256, 0, stream>>>((const unsigned*)d_in[6], flag);

  struct { const void* s; unsigned short* d; int n; } cv[9] = {
    { d_in[4],  Wemb_c,  FEAT * EMB },
    { d_in[5],  bemb_c,  EMB },
    { d_in[6],  Wih_c,   G4 * XDIM },
    { d_in[7],  Whh_c,   G4 * HID },
    { d_in[8],  blstm_c, G4 },
    { d_in[9],  W1_c,    HID * HID },
    { d_in[10], b1_c,    HID },
    { d_in[11], W2_c,    HID * 10 },
    { d_in[12], b2_c,    10 },
  };
  for (int i = 0; i < 9; ++i)
    k_convert<<<(cv[i].n + 255) / 256, 256, 0, stream>>>(cv[i].s, cv[i].d, cv[i].n, flag);

  k_hist<<<E_EDGESN / 256, 256, 0, stream>>>(nid, ntag, hist);
  k_build_x<<<N_NODES, 256, 0, stream>>>(node_tags, hist, Wemb_c, bemb_c, x);
  k_gemm_pre<<<dim3(G4 / 128, N_NODES / 64), 256, 0, stream>>>(x, Wih_c, blstm_c, pre);
  k_scan<<<NWG, 256, 0, stream>>>(Whh_c, pre, hw, embed);
  k_head<<<1, 512, 0, stream>>>(embed, W1_c, b1_c, W2_c, b2_c, d_out, flag);
}